// Round 1
// baseline (214.378 us; speedup 1.0000x reference)
//
#include <hip/hip_runtime.h>

// Problem constants (from reference)
#define N_REGIONS 1024
#define N_PIXELS  131072   // 2^17
#define DIM       64

// ---------------------------------------------------------------------------
// Kernel 0: zero the output (d_out is poisoned 0xAA and never re-poisoned
// between timed replays; we accumulate with atomics, so zero it each call).
// ---------------------------------------------------------------------------
__global__ void zero_out_kernel(float* __restrict__ out) {
    int i = blockIdx.x * blockDim.x + threadIdx.x;
    if (i < N_REGIONS * DIM) out[i] = 0.0f;
}

// ---------------------------------------------------------------------------
// Kernel 1: scan the one-hot mask [R=1024][P=131072] row-major with float4
// loads (fully coalesced). For each nonzero element (exactly one per pixel
// column), record seg[p] = r.  This is the 512 MiB read that dominates.
// ---------------------------------------------------------------------------
__global__ void find_seg_kernel(const float4* __restrict__ mask4,
                                int* __restrict__ seg) {
    const long long total4 = (long long)N_REGIONS * N_PIXELS / 4;  // 33,554,432
    const long long stride = (long long)gridDim.x * blockDim.x;
    for (long long i = (long long)blockIdx.x * blockDim.x + threadIdx.x;
         i < total4; i += stride) {
        float4 v = mask4[i];
        // rare path: ~1 in 256 float4s contains the single 1.0 of a column
        if (v.x != 0.0f || v.y != 0.0f || v.z != 0.0f || v.w != 0.0f) {
            long long e = i * 4;                 // flat element index
            int r     = (int)(e >> 17);          // row = e / N_PIXELS
            int pbase = (int)(e & (N_PIXELS - 1));
            if (v.x != 0.0f) seg[pbase + 0] = r;
            if (v.y != 0.0f) seg[pbase + 1] = r;
            if (v.z != 0.0f) seg[pbase + 2] = r;
            if (v.w != 0.0f) seg[pbase + 3] = r;
        }
    }
}

// ---------------------------------------------------------------------------
// Kernel 2: segment-sum of x [P][64] into out [R][64] via hardware fp32
// atomics. Each thread handles one float4 (4 consecutive dims of one pixel):
// coalesced 32 MiB read of x, 4 atomicAdds to the 256 KiB output table.
// ---------------------------------------------------------------------------
__global__ void scatter_add_kernel(const float4* __restrict__ x4,
                                   const int* __restrict__ seg,
                                   float* __restrict__ out) {
    const int total4 = N_PIXELS * DIM / 4;  // 2,097,152
    const int stride = gridDim.x * blockDim.x;
    for (int i = blockIdx.x * blockDim.x + threadIdx.x;
         i < total4; i += stride) {
        int p  = i >> 4;      // 16 float4 per pixel row (64 dims)
        int d4 = i & 15;
        float4 v = x4[i];
        int r = seg[p];
        float* o = out + r * DIM + d4 * 4;
        unsafeAtomicAdd(o + 0, v.x);
        unsafeAtomicAdd(o + 1, v.y);
        unsafeAtomicAdd(o + 2, v.z);
        unsafeAtomicAdd(o + 3, v.w);
    }
}

extern "C" void kernel_launch(void* const* d_in, const int* in_sizes, int n_in,
                              void* d_out, int out_size, void* d_ws, size_t ws_size,
                              hipStream_t stream) {
    const float* mask = (const float*)d_in[0];   // [1024][131072] fp32 one-hot
    const float* x    = (const float*)d_in[1];   // [131072][64] fp32
    float* out        = (float*)d_out;           // [1024][64] fp32
    int*   seg        = (int*)d_ws;              // 131072 ints = 512 KiB scratch

    // 0) zero output (stream-ordered before the atomics)
    zero_out_kernel<<<(N_REGIONS * DIM + 255) / 256, 256, 0, stream>>>(out);

    // 1) recover seg[p] from the one-hot mask (the 512 MiB coalesced read)
    find_seg_kernel<<<2048, 256, 0, stream>>>((const float4*)mask, seg);

    // 2) segment-sum x into out (32 MiB read + 8.4M fp32 atomics)
    scatter_add_kernel<<<2048, 256, 0, stream>>>((const float4*)x, seg, out);
}